// Round 16
// baseline (199.311 us; speedup 1.0000x reference)
//
#include <hip/hip_runtime.h>
#include <hip/hip_bf16.h>

typedef __attribute__((ext_vector_type(4))) short bfx4;
typedef __attribute__((ext_vector_type(8))) short short8;
typedef __attribute__((ext_vector_type(4))) float floatx4;
typedef __attribute__((ext_vector_type(16))) float f32x16;
typedef __attribute__((ext_vector_type(4))) unsigned int uintx4;

constexpr int Sdim = 2048;
constexpr int Hdim = 1024;
constexpr int NH   = 16;
constexpr int HD   = 64;

constexpr float L2E    = 1.4426950408889634f;   // log2(e)
constexpr float SHIFT2 = 17.312340490667562f;   // 12 * log2(e)

// fp32 -> bf16 round-half-up (1 add + shift)
__device__ __forceinline__ unsigned short f2bf(float f) {
    return (unsigned short)((__builtin_bit_cast(unsigned int, f) + 0x8000u) >> 16);
}

// 8 fp32 -> 8 bf16, round-half-up, packed with v_perm_b32
__device__ __forceinline__ short8 cvt8(const float* __restrict__ p) {
    uintx4 a = *(const uintx4*)p;
    uintx4 b = *(const uintx4*)(p + 4);
#pragma unroll
    for (int i = 0; i < 4; ++i) { a[i] += 0x8000u; b[i] += 0x8000u; }
    union { unsigned int u[4]; short8 s; } r;
    r.u[0] = __builtin_amdgcn_perm(a[1], a[0], 0x07060302u);
    r.u[1] = __builtin_amdgcn_perm(a[3], a[2], 0x07060302u);
    r.u[2] = __builtin_amdgcn_perm(b[1], b[0], 0x07060302u);
    r.u[3] = __builtin_amdgcn_perm(b[3], b[2], 0x07060302u);
    return r.s;
}

// async global->LDS, 16 B per lane; LDS dest = uniform base + lane*16
__device__ __forceinline__ void async16(const unsigned short* g, unsigned short* l) {
    __builtin_amdgcn_global_load_lds(
        (const __attribute__((address_space(1))) unsigned int*)g,
        (__attribute__((address_space(3))) unsigned int*)l,
        16, 0, 0);
}

// pack 2 f32 -> 2 bf16 (RNE) in one instruction
__device__ __forceinline__ unsigned int cvtpk(float lo, float hi) {
    unsigned int r;
    asm("v_cvt_pk_bf16_f32 %0, %1, %2" : "=v"(r) : "v"(lo), "v"(hi));
    return r;
}

// bare v_exp_f32: D = 2^S0
__device__ __forceinline__ float exp2_raw(float x) {
    float r;
    asm("v_exp_f32 %0, %1" : "=v"(r) : "v"(x));
    return r;
}

// ---------------------------------------------------------------------------
// Kernel 0: cast X, Wq, Wk, Wv to bf16; prescale mask to m*log2e - 12*log2e.
// (UNCHANGED — control.)
// ---------------------------------------------------------------------------
__global__ __launch_bounds__(256) void cast_kernel(
    const float* __restrict__ X,
    const float* __restrict__ Wq,
    const float* __restrict__ Wk,
    const float* __restrict__ Wv,
    const float* __restrict__ mask,
    unsigned short* __restrict__ xb,
    unsigned short* __restrict__ wb,
    float* __restrict__ mb)
{
    constexpr int XC = (2 * Sdim * Hdim) / 8;   // 524288 8-elem chunks
    constexpr int WC = (Hdim * Hdim) / 8;       // 131072 chunks per W
    constexpr int MC = (2 * Sdim) / 8;          // 512 mask chunks
    const int stride = gridDim.x * blockDim.x;
    for (int c = blockIdx.x * blockDim.x + threadIdx.x; c < XC + 3 * WC + MC; c += stride) {
        if (c < XC + 3 * WC) {
            const float* src;
            unsigned short* dst;
            if (c < XC) {
                src = X + (size_t)c * 8;
                dst = xb + (size_t)c * 8;
            } else {
                const int wc = c - XC;
                const int w  = wc / WC;
                const int o  = wc - w * WC;
                src = (w == 0 ? Wq : (w == 1 ? Wk : Wv)) + (size_t)o * 8;
                dst = wb + (size_t)w * (Hdim * Hdim) + (size_t)o * 8;
            }
            *(short8*)dst = cvt8(src);
        } else {
            const int o = c - XC - 3 * WC;
            floatx4 a = *(const floatx4*)(mask + (size_t)o * 8);
            floatx4 b = *(const floatx4*)(mask + (size_t)o * 8 + 4);
#pragma unroll
            for (int r = 0; r < 4; ++r) {
                a[r] = a[r] * L2E - SHIFT2;
                b[r] = b[r] * L2E - SHIFT2;
            }
            *(floatx4*)(mb + (size_t)o * 8)     = a;
            *(floatx4*)(mb + (size_t)o * 8 + 4) = b;
        }
    }
}

// ---------------------------------------------------------------------------
// Kernel 1: merged Q/K/V projection. R16: 32-ROW m-tiles (grid 16x128,
// 2048 blocks -> 8192 total waves, 2x parallelism; LDS 2x14336 B = 28672 B
// -> 5 blocks/CU resident, 20 waves/CU vs 16). Staging: 14 chunks of
// 16 rows ({X:2, W0..2:4 each}); wave w stages chunks {w, w+4, w+8,
// (+w+12 if w<2)} via global_load_lds, same R9 chunk swizzle
// (src col-piece = (lane&3) ^ ((lane>>3)&3); reads use fR=(l16>>1)&3).
// Per wave per step: 6 MFMA (3 matrices x 2 m-tiles) + 5 ds_read_b128.
// ---------------------------------------------------------------------------
__global__ __launch_bounds__(256, 4) void qkv_proj_kernel(
    const unsigned short* __restrict__ wbf,   // [3][1024][1024] bf16
    const float* __restrict__ bq,
    const float* __restrict__ bv,
    const unsigned short* __restrict__ xbf,   // [4096][1024] bf16
    unsigned short* __restrict__ qo,          // = d_out viewed as ushort
    unsigned short* __restrict__ ko,
    unsigned short* __restrict__ vo)
{
    __shared__ __align__(16) unsigned short smem[2 * 7168];   // 28672 B
    // buffer p: +p*7168 shorts; X +0 (32 rows), W0 +1024, W1 +3072, W2 +5120
    // (row = 32 shorts)

    const int tid  = threadIdx.x;
    const int wave = tid >> 6;
    const int lane = tid & 63;
    const int quad = lane >> 4;
    const int l16  = lane & 15;

    const int h  = blockIdx.x;
    const int n0 = h * 64;
    const int m0 = blockIdx.y * 32;

    floatx4 acc[3][2];                   // [matrix][m-tile]
#pragma unroll
    for (int g = 0; g < 3; ++g)
#pragma unroll
        for (int mt = 0; mt < 2; ++mt) acc[g][mt] = (floatx4){0.f, 0.f, 0.f, 0.f};

    // ---- DMA chunk sources: chunk c = 16 rows; lane -> row +lane>>2,
    //      16B piece (lane&3)^fD, fD = (lane>>3)&3 (row-bit 1..2 of lane>>2)
    const int drow = lane >> 2;              // 0..15
    const int csw  = (((lane & 3) ^ ((lane >> 3) & 3)) * 8);

    const unsigned short* cp[4];
    int ldo[4];
    const int nck = (wave < 2) ? 4 : 3;
#pragma unroll
    for (int i = 0; i < 4; ++i) {
        const int c = wave + 4 * i;
        if (i < nck) {
            if (c < 2) {
                cp[i]  = xbf + (size_t)(m0 + c * 16 + drow) * Hdim + csw;
                ldo[i] = c * 512;
            } else {
                const int mat = (c - 2) >> 2;
                const int r0  = ((c - 2) & 3) * 16;
                cp[i]  = wbf + (size_t)mat * (Hdim * Hdim)
                             + (size_t)(n0 + r0 + drow) * Hdim + csw;
                ldo[i] = 1024 + mat * 2048 + r0 * 32;
            }
        } else { cp[i] = nullptr; ldo[i] = 0; }
    }

    // stage step 0 -> buffer 0
    {
        unsigned short* db = smem;
        async16(cp[0], db + ldo[0]);
        async16(cp[1], db + ldo[1]);
        async16(cp[2], db + ldo[2]);
        if (wave < 2) async16(cp[3], db + ldo[3]);
    }

    // fragment read offset (shorts); fR = (row>>1)&3 with row = {mt,wave}*16+l16
    // -> (l16>>1)&3 since mt*16/wave*16 don't touch bits 1..2
    const int cswz = ((quad ^ ((l16 >> 1) & 3)) * 8);
    const int boff = (wave * 16 + l16) * 32 + cswz;

    for (int s = 0; s < 32; ++s) {
        __syncthreads();                              // drain DMA: tile s ready
        const unsigned short* buf = smem + (s & 1) * 7168;

        if (s < 31) {                                 // DMA next step -> other buffer
            unsigned short* nb = smem + ((s & 1) ^ 1) * 7168;
            const int kn = (s + 1) * 32;
            async16(cp[0] + kn, nb + ldo[0]);
            async16(cp[1] + kn, nb + ldo[1]);
            async16(cp[2] + kn, nb + ldo[2]);
            if (wave < 2) async16(cp[3] + kn, nb + ldo[3]);
        }

        const short8 b0 = *(const short8*)(buf + 1024 + boff);
        const short8 b1 = *(const short8*)(buf + 3072 + boff);
        const short8 b2 = *(const short8*)(buf + 5120 + boff);
#pragma unroll
        for (int mt = 0; mt < 2; ++mt) {
            const short8 af = *(const short8*)(buf + (mt * 16 + l16) * 32 + cswz);
            acc[0][mt] = __builtin_amdgcn_mfma_f32_16x16x32_bf16(af, b0, acc[0][mt], 0, 0, 0);
            acc[1][mt] = __builtin_amdgcn_mfma_f32_16x16x32_bf16(af, b1, acc[1][mt], 0, 0, 0);
            acc[2][mt] = __builtin_amdgcn_mfma_f32_16x16x32_bf16(af, b2, acc[2][mt], 0, 0, 0);
        }
    }

    const int b  = m0 >> 11;
    const int s0 = m0 & 2047;
    const int dd = wave * 16 + l16;

    // ---- Q epilogue: bf16, scale = 0.125*log2e (exp2-ready) ----
    {
        const float bqv = bq[n0 + dd];
#pragma unroll
        for (int mt = 0; mt < 2; ++mt)
#pragma unroll
            for (int reg = 0; reg < 4; ++reg) {
                const int srw = s0 + mt * 16 + quad * 4 + reg;
                qo[((size_t)(b * Sdim + srw) * Hdim + n0) * 2 + dd] =
                    f2bf((acc[0][mt][reg] + bqv) * (0.125f * L2E));
            }
    }
    // ---- K epilogue: bf16 [b,h,s,d] ----
#pragma unroll
    for (int mt = 0; mt < 2; ++mt)
#pragma unroll
        for (int reg = 0; reg < 4; ++reg) {
            const int srw = s0 + mt * 16 + quad * 4 + reg;
            ko[((size_t)(b * NH + h) * Sdim + srw) * HD + dd] = f2bf(acc[1][mt][reg]);
        }
    // ---- V epilogue: transpose via LDS buf0 (last step read buf1: disjoint) ----
    unsigned short* Vl = smem;   // 64 rows x 40 shorts = 2560 <= 7168
    {
        const float bvv = bv[n0 + dd];
#pragma unroll
        for (int mt = 0; mt < 2; ++mt) {
            bfx4 p;
#pragma unroll
            for (int reg = 0; reg < 4; ++reg) p[reg] = (short)f2bf(acc[2][mt][reg] + bvv);
            *(bfx4*)(Vl + dd * 40 + mt * 16 + quad * 4) = p;
        }
    }
    __syncthreads();
    {
        const int d2  = tid >> 2;          // 0..63
        const int off = (tid & 3) * 8;     // 0..24
        *(short8*)(vo + ((size_t)(b * NH + h) * HD + d2) * Sdim + s0 + off) =
            *(const short8*)(Vl + d2 * 40 + off);
    }
}

// ---------------------------------------------------------------------------
// Kernel 2: flash attention on 32x32x16 MFMA — EXACT R14 (proven 70.7 us,
// VGPR=64 occupancy cliff edge; R15's +12 VGPR cost 5 us — reverted).
// ---------------------------------------------------------------------------
__global__ __launch_bounds__(256) void attn_kernel(
    const unsigned short* __restrict__ kw,
    const unsigned short* __restrict__ vw,
    const float* __restrict__ mb,          // prescaled mask: m*log2e - 12*log2e
    float* __restrict__ out)
{
    __shared__ __align__(16) unsigned short smem[16384];   // 32768 B
    unsigned short* KtA = smem;            // 2 x 4096 shorts (64 keys x 64 d, swizzled)
    unsigned short* VtA = smem + 8192;     // 2 x 4096 shorts (64 d x 64 keys, swizzled)

    const int tid  = threadIdx.x;
    const int wave = tid >> 6;
    const int wq   = wave >> 1;            // q-half 0/1
    const int wk   = wave & 1;             // key-half 0/1
    const int lane = tid & 63;
    const int l5   = lane >> 5;            // lane-half
    const int q31  = lane & 31;            // this lane's q column (C layout)
    const int m7l  = lane & 7;

    const int flat = blockIdx.x;
    const int bh   = flat & 31;
    const int b    = bh >> 4;
    const int h    = bh & 15;
    const int q0   = (flat >> 5) * 64;

    const unsigned short* K  = kw + (size_t)bh * Sdim * HD;   // [key][d]
    const unsigned short* Vg = vw + (size_t)bh * HD * Sdim;   // [d][key]
    const float* mg = mb + (size_t)b * Sdim;

    // ---- Q fragments (B-operand, 32x32x16): lane holds col q31, k = i*16+l5*8 ----
    short8 qf[4];
    {
        const unsigned short* qsrc = (const unsigned short*)out;
        const size_t qbase =
            ((size_t)(b * Sdim + q0 + wq * 32 + q31) * Hdim + h * HD) * 2;
#pragma unroll
        for (int i = 0; i < 4; ++i)
            qf[i] = *(const short8*)(qsrc + qbase + i * 16 + l5 * 8);
    }

    // ---- DMA lane mapping: lane covers row rk, global chunk XOR-swizzled ----
    const int rk = wave * 16 + (lane >> 3);
    const int sw = ((lane & 7) ^ (rk & 7)) * 8;
    const unsigned short* kgp = K  + (size_t)rk * HD   + sw;
    const unsigned short* vgp = Vg + (size_t)rk * Sdim + sw;

    // stage tile 0 -> buffer 0
    {
        unsigned short* Kb = KtA + wave * 1024;
        unsigned short* Vb = VtA + wave * 1024;
        async16(kgp,            Kb);
        async16(kgp + 8 * HD,   Kb + 512);
        async16(vgp,            Vb);
        async16(vgp + 8 * Sdim, Vb + 512);
        kgp += (size_t)64 * HD;
        vgp += 64;
    }

    // tile-invariant LDS read offsets (shorts); row&7 == lane&7 for both
    int kOff[4], vOff[4];
#pragma unroll
    for (int i = 0; i < 4; ++i)
        kOff[i] = (wk * 32 + q31) * 64 + (((2 * i + l5) ^ m7l) * 8);
#pragma unroll
    for (int dblk = 0; dblk < 2; ++dblk)
#pragma unroll
        for (int kc = 0; kc < 2; ++kc)
            vOff[dblk * 2 + kc] =
                (dblk * 32 + q31) * 64 + (((wk * 4 + 2 * kc + l5) ^ m7l) * 8);

    const float* mgp = mg + wk * 32 + l5 * 4;

    float ls[4] = {0.f, 0.f, 0.f, 0.f};   // 4 independent lsum chains
    f32x16 oT[2];                          // O^T per 32-d block; col=q31
#pragma unroll
    for (int dblk = 0; dblk < 2; ++dblk)
#pragma unroll
        for (int r = 0; r < 16; ++r) oT[dblk][r] = 0.f;

    f32x16 z16;                            // loop-invariant zero accumulator
#pragma unroll
    for (int r = 0; r < 16; ++r) z16[r] = 0.f;

    for (int it = 0; it < 32; ++it) {
        __syncthreads();                   // vmcnt drain + barrier: tile ready
        const int kt = it * 64;
        const unsigned short* Kb = KtA + (it & 1) * 4096;
        const unsigned short* Vb = VtA + (it & 1) * 4096;

        if (it < 31) {                     // DMA next tile into other buffer
            unsigned short* Kn = KtA + ((it & 1) ^ 1) * 4096 + wave * 1024;
            unsigned short* Vn = VtA + ((it & 1) ^ 1) * 4096 + wave * 1024;
            async16(kgp,            Kn);
            async16(kgp + 8 * HD,   Kn + 512);
            async16(vgp,            Vn);
            async16(vgp + 8 * Sdim, Vn + 512);
            kgp += (size_t)64 * HD;
            vgp += 64;
        }

        // ---- S^T = K·Q^T: 4 chained 32x32x16 over d; first uses z16 as C ----
        f32x16 st;
        {
            const short8 ka0 = *(const short8*)(Kb + kOff[0]);
            st = __builtin_amdgcn_mfma_f32_32x32x16_bf16(ka0, qf[0], z16, 0, 0, 0);
        }
#pragma unroll
        for (int i = 1; i < 4; ++i) {
            const short8 ka = *(const short8*)(Kb + kOff[i]);
            st = __builtin_amdgcn_mfma_f32_32x32x16_bf16(ka, qf[i], st, 0, 0, 0);
        }

        // ---- raw v_exp_f32 + in-reg bf16 pack; st reg r -> key (r&3)+8*(r>>2)+4*l5
        unsigned int w[8];
#pragma unroll
        for (int j = 0; j < 4; ++j) {
            const floatx4 mv = *(const floatx4*)(mgp + kt + j * 8);
            float e[4];
#pragma unroll
            for (int r = 0; r < 4; ++r)
                e[r] = exp2_raw(st[j * 4 + r] + mv[r]);
            ls[j] += (e[0] + e[1]) + (e[2] + e[3]);
            w[2 * j]     = cvtpk(e[0], e[1]);
            w[2 * j + 1] = cvtpk(e[2], e[3]);
        }

        // ---- cross-half exchange: 4 x v_permlane32_swap ----
        asm("v_permlane32_swap_b32 %0, %1" : "+v"(w[0]), "+v"(w[2]));
        asm("v_permlane32_swap_b32 %0, %1" : "+v"(w[1]), "+v"(w[3]));
        asm("v_permlane32_swap_b32 %0, %1" : "+v"(w[4]), "+v"(w[6]));
        asm("v_permlane32_swap_b32 %0, %1" : "+v"(w[5]), "+v"(w[7]));
        union { unsigned int u[4]; short8 s; } pb0, pb1;
#pragma unroll
        for (int r = 0; r < 4; ++r) { pb0.u[r] = w[r]; pb1.u[r] = w[4 + r]; }

        // ---- O^T += V^T·P^T: 2 d-blocks x 2 key-chunks (keys wk*32+kc*16+..) ----
#pragma unroll
        for (int dblk = 0; dblk < 2; ++dblk) {
            const short8 va0 = *(const short8*)(Vb + vOff[dblk * 2 + 0]);
            oT[dblk] = __builtin_amdgcn_mfma_f32_32x32x16_bf16(va0, pb0.s, oT[dblk], 0, 0, 0);
            const short8 va1 = *(const short8*)(Vb + vOff[dblk * 2 + 1]);
            oT[dblk] = __builtin_amdgcn_mfma_f32_32x32x16_bf16(va1, pb1.s, oT[dblk], 0, 0, 0);
        }
    }

    // ---- combine chains + lane halves: full 32-key sum for this key-half ----
    float lsum = (ls[0] + ls[1]) + (ls[2] + ls[3]);
    lsum += __shfl_xor(lsum, 32);

    __syncthreads();                       // all waves done with K/V buffers

    // ---- cross-wave (key-half) reduction via LDS, then write out ----
    float* Ored = (float*)smem;            // [64 q][68 d] fp32 (17408 B)
    float* Lred = Ored + 64 * 68;          // [64]
    const int qrow = wq * 32 + q31;
    if (wk == 0) {
#pragma unroll
        for (int dblk = 0; dblk < 2; ++dblk)
#pragma unroll
            for (int j = 0; j < 4; ++j) {
                floatx4 v;
#pragma unroll
                for (int r = 0; r < 4; ++r) v[r] = oT[dblk][j * 4 + r];
                *(floatx4*)(Ored + (size_t)qrow * 68 + dblk * 32 + j * 8 + l5 * 4) = v;
            }
        if (lane < 32) Lred[qrow] = lsum;
    }
    __syncthreads();
    if (wk == 1) {
        const float linv = 1.0f / (lsum + Lred[qrow]);
#pragma unroll
        for (int dblk = 0; dblk < 2; ++dblk)
#pragma unroll
            for (int j = 0; j < 4; ++j) {
                const floatx4 o =
                    *(const floatx4*)(Ored + (size_t)qrow * 68 + dblk * 32 + j * 8 + l5 * 4);
                floatx4 r;
#pragma unroll
                for (int t = 0; t < 4; ++t)
                    r[t] = (o[t] + oT[dblk][j * 4 + t]) * linv;
                *(floatx4*)(out + (size_t)(b * Sdim + q0 + qrow) * Hdim
                            + h * HD + dblk * 32 + j * 8 + l5 * 4) = r;
            }
    }
}

extern "C" void kernel_launch(void* const* d_in, const int* in_sizes, int n_in,
                              void* d_out, int out_size, void* d_ws, size_t ws_size,
                              hipStream_t stream) {
    const float* X    = (const float*)d_in[0];
    const float* mask = (const float*)d_in[1];
    const float* Wq   = (const float*)d_in[2];
    const float* bq   = (const float*)d_in[3];
    const float* Wk   = (const float*)d_in[4];
    const float* Wv   = (const float*)d_in[5];
    const float* bv   = (const float*)d_in[6];
    float* out = (float*)d_out;

    // workspace (30.02 MiB): k 8 + v^T 8 + X_bf16 8 + W_bf16 6 + mask2 16KB
    unsigned short* kws = (unsigned short*)d_ws;
    unsigned short* vws = kws + (size_t)4096 * 1024;
    unsigned short* xb  = vws + (size_t)4096 * 1024;
    unsigned short* wb  = xb  + (size_t)2 * Sdim * Hdim;
    float*          mb  = (float*)(wb + (size_t)3 * Hdim * Hdim);

    cast_kernel<<<dim3(2048), 256, 0, stream>>>(X, Wq, Wk, Wv, mask, xb, wb, mb);
    qkv_proj_kernel<<<dim3(16, 128), 256, 0, stream>>>(
        wb, bq, bv, xb, (unsigned short*)d_out, kws, vws);
    attn_kernel<<<dim3(1024), 256, 0, stream>>>(
        kws, vws, mb, out);
}

// Round 17
// 185.321 us; speedup vs baseline: 1.0755x; 1.0755x over previous
//
#include <hip/hip_runtime.h>
#include <hip/hip_bf16.h>

typedef __attribute__((ext_vector_type(4))) short bfx4;
typedef __attribute__((ext_vector_type(8))) short short8;
typedef __attribute__((ext_vector_type(4))) float floatx4;
typedef __attribute__((ext_vector_type(16))) float f32x16;
typedef __attribute__((ext_vector_type(4))) unsigned int uintx4;

constexpr int Sdim = 2048;
constexpr int Hdim = 1024;
constexpr int NH   = 16;
constexpr int HD   = 64;

constexpr float L2E    = 1.4426950408889634f;   // log2(e)
constexpr float SHIFT2 = 17.312340490667562f;   // 12 * log2(e)

// fp32 -> bf16 round-half-up (1 add + shift)
__device__ __forceinline__ unsigned short f2bf(float f) {
    return (unsigned short)((__builtin_bit_cast(unsigned int, f) + 0x8000u) >> 16);
}

// 8 fp32 -> 8 bf16, round-half-up, packed with v_perm_b32
__device__ __forceinline__ short8 cvt8(const float* __restrict__ p) {
    uintx4 a = *(const uintx4*)p;
    uintx4 b = *(const uintx4*)(p + 4);
#pragma unroll
    for (int i = 0; i < 4; ++i) { a[i] += 0x8000u; b[i] += 0x8000u; }
    union { unsigned int u[4]; short8 s; } r;
    r.u[0] = __builtin_amdgcn_perm(a[1], a[0], 0x07060302u);
    r.u[1] = __builtin_amdgcn_perm(a[3], a[2], 0x07060302u);
    r.u[2] = __builtin_amdgcn_perm(b[1], b[0], 0x07060302u);
    r.u[3] = __builtin_amdgcn_perm(b[3], b[2], 0x07060302u);
    return r.s;
}

// async global->LDS, 16 B per lane; LDS dest = uniform base + lane*16
__device__ __forceinline__ void async16(const unsigned short* g, unsigned short* l) {
    __builtin_amdgcn_global_load_lds(
        (const __attribute__((address_space(1))) unsigned int*)g,
        (__attribute__((address_space(3))) unsigned int*)l,
        16, 0, 0);
}

// pack 2 f32 -> 2 bf16 (RNE) in one instruction
__device__ __forceinline__ unsigned int cvtpk(float lo, float hi) {
    unsigned int r;
    asm("v_cvt_pk_bf16_f32 %0, %1, %2" : "=v"(r) : "v"(lo), "v"(hi));
    return r;
}

// bare v_exp_f32: D = 2^S0
__device__ __forceinline__ float exp2_raw(float x) {
    float r;
    asm("v_exp_f32 %0, %1" : "=v"(r) : "v"(x));
    return r;
}

// ---------------------------------------------------------------------------
// Kernel 0: cast X, Wq, Wk, Wv to bf16; prescale mask to m*log2e - 12*log2e.
// (UNCHANGED — control.)
// ---------------------------------------------------------------------------
__global__ __launch_bounds__(256) void cast_kernel(
    const float* __restrict__ X,
    const float* __restrict__ Wq,
    const float* __restrict__ Wk,
    const float* __restrict__ Wv,
    const float* __restrict__ mask,
    unsigned short* __restrict__ xb,
    unsigned short* __restrict__ wb,
    float* __restrict__ mb)
{
    constexpr int XC = (2 * Sdim * Hdim) / 8;   // 524288 8-elem chunks
    constexpr int WC = (Hdim * Hdim) / 8;       // 131072 chunks per W
    constexpr int MC = (2 * Sdim) / 8;          // 512 mask chunks
    const int stride = gridDim.x * blockDim.x;
    for (int c = blockIdx.x * blockDim.x + threadIdx.x; c < XC + 3 * WC + MC; c += stride) {
        if (c < XC + 3 * WC) {
            const float* src;
            unsigned short* dst;
            if (c < XC) {
                src = X + (size_t)c * 8;
                dst = xb + (size_t)c * 8;
            } else {
                const int wc = c - XC;
                const int w  = wc / WC;
                const int o  = wc - w * WC;
                src = (w == 0 ? Wq : (w == 1 ? Wk : Wv)) + (size_t)o * 8;
                dst = wb + (size_t)w * (Hdim * Hdim) + (size_t)o * 8;
            }
            *(short8*)dst = cvt8(src);
        } else {
            const int o = c - XC - 3 * WC;
            floatx4 a = *(const floatx4*)(mask + (size_t)o * 8);
            floatx4 b = *(const floatx4*)(mask + (size_t)o * 8 + 4);
#pragma unroll
            for (int r = 0; r < 4; ++r) {
                a[r] = a[r] * L2E - SHIFT2;
                b[r] = b[r] * L2E - SHIFT2;
            }
            *(floatx4*)(mb + (size_t)o * 8)     = a;
            *(floatx4*)(mb + (size_t)o * 8 + 4) = b;
        }
    }
}

// ---------------------------------------------------------------------------
// Kernel 1: merged Q/K/V projection. R17: R14's 64-row geometry, but the
// sync structure is RING-3 + COUNTED VMCNT (T4): 3 LDS buffers (48 KiB),
// prefetch distance 2, raw s_barrier, s_waitcnt vmcnt(4) in the loop
// (never 0 — step-s+1's loads stay in flight across the barrier).
// Iteration: wait vmcnt(4) [retires step-s loads] -> s_barrier -> issue
// step-s+2 into buf[(s+2)%3] (safe: barrier proved everyone left s-1)
// -> compute step s. Loads get ~2 iterations to land instead of ~1.
// bq/bv VMEM loads hoisted BEFORE the first async16 (vmcnt ledger safety).
// Cost: 3 blocks/CU (12 waves) vs 4 (16) — latency-vs-occupancy trade.
// grid = (16 heads, 64 m-tiles); block = 256.
// ---------------------------------------------------------------------------
__global__ __launch_bounds__(256, 4) void qkv_proj_kernel(
    const unsigned short* __restrict__ wbf,   // [3][1024][1024] bf16
    const float* __restrict__ bq,
    const float* __restrict__ bv,
    const unsigned short* __restrict__ xbf,   // [4096][1024] bf16
    unsigned short* __restrict__ qo,          // = d_out viewed as ushort
    unsigned short* __restrict__ ko,
    unsigned short* __restrict__ vo)
{
    __shared__ __align__(16) unsigned short smem[3 * 8192];   // 49152 B
    // buffer p: +p*8192 shorts; tiles: X +0, W0 +2048, W1 +4096, W2 +6144

    const int tid  = threadIdx.x;
    const int wave = tid >> 6;
    const int lane = tid & 63;
    const int quad = lane >> 4;
    const int l16  = lane & 15;

    const int h  = blockIdx.x;
    const int n0 = h * 64;
    const int m0 = blockIdx.y * 64;
    const int dd = wave * 16 + l16;

    // hoisted VMEM loads (must retire before the staging ledger starts)
    const float bqv = bq[n0 + dd];
    const float bvv = bv[n0 + dd];

    floatx4 acc[3][4];                   // [matrix][m-tile]
#pragma unroll
    for (int g = 0; g < 3; ++g)
#pragma unroll
        for (int mt = 0; mt < 4; ++mt) acc[g][mt] = (floatx4){0.f, 0.f, 0.f, 0.f};

    // ---- DMA source mapping: lane -> row j*16 + (lane>>2), chunk lane&3 ----
    const int drow   = lane >> 2;            // 0..15
    const int dchunk = lane & 3;
    const int fD     = (drow >> 1) & 3;      // (row>>1)&3; j*16 doesn't affect it
    const unsigned short* gbase = (wave == 0)
        ? xbf + (size_t)m0 * Hdim
        : wbf + (size_t)(wave - 1) * (Hdim * Hdim) + (size_t)n0 * Hdim;
    const unsigned short* gp =
        gbase + (size_t)drow * Hdim + ((dchunk ^ fD) * 8);

    // prologue: stage step 0 -> buf0, step 1 -> buf1 (8 loads outstanding)
    {
        unsigned short* d0 = smem +        wave * 2048;
        unsigned short* d1 = smem + 8192 + wave * 2048;
#pragma unroll
        for (int j = 0; j < 4; ++j) {
            async16(gp      + (size_t)(j * 16) * Hdim, d0 + j * 512);
        }
#pragma unroll
        for (int j = 0; j < 4; ++j) {
            async16(gp + 32 + (size_t)(j * 16) * Hdim, d1 + j * 512);
        }
    }

    // fragment read offset (shorts), step-invariant; f = (l16>>1)&3 since
    // mt*16 / wave*16 don't touch bits 1..2 of the row
    const int fR   = (l16 >> 1) & 3;
    const int cswz = (quad ^ fR) * 8;
    const int boff = (wave * 16 + l16) * 32 + cswz;

    int rb  = 0;   // read buffer for step s
    int wb2 = 2;   // write buffer for step s+2
    for (int s = 0; s < 32; ++s) {
        // retire step-s loads; keep step-s+1 in flight (counted vmcnt, T4)
        if (s < 31) asm volatile("s_waitcnt vmcnt(4)" ::: "memory");
        else        asm volatile("s_waitcnt vmcnt(0)" ::: "memory");
        __builtin_amdgcn_s_barrier();     // raw: no compiler vmcnt(0) drain

        if (s < 30) {                     // prefetch step s+2 (post-barrier)
            unsigned short* nb = smem + wb2 * 8192 + wave * 2048;
            const unsigned short* g = gp + (s + 2) * 32;
#pragma unroll
            for (int j = 0; j < 4; ++j)
                async16(g + (size_t)(j * 16) * Hdim, nb + j * 512);
        }

        const unsigned short* buf = smem + rb * 8192;
        const short8 b0 = *(const short8*)(buf + 2048 + boff);
        const short8 b1 = *(const short8*)(buf + 4096 + boff);
        const short8 b2 = *(const short8*)(buf + 6144 + boff);
#pragma unroll
        for (int mt = 0; mt < 4; ++mt) {
            const short8 af = *(const short8*)(buf + (mt * 16 + l16) * 32 + cswz);
            acc[0][mt] = __builtin_amdgcn_mfma_f32_16x16x32_bf16(af, b0, acc[0][mt], 0, 0, 0);
            acc[1][mt] = __builtin_amdgcn_mfma_f32_16x16x32_bf16(af, b1, acc[1][mt], 0, 0, 0);
            acc[2][mt] = __builtin_amdgcn_mfma_f32_16x16x32_bf16(af, b2, acc[2][mt], 0, 0, 0);
        }

        rb  = (rb  == 2) ? 0 : rb  + 1;
        wb2 = (wb2 == 2) ? 0 : wb2 + 1;
    }

    const int b  = m0 >> 11;
    const int s0 = m0 & 2047;

    // ---- Q epilogue: bf16, scale = 0.125*log2e (exp2-ready) ----
#pragma unroll
    for (int mt = 0; mt < 4; ++mt)
#pragma unroll
        for (int reg = 0; reg < 4; ++reg) {
            const int srw = s0 + mt * 16 + quad * 4 + reg;
            qo[((size_t)(b * Sdim + srw) * Hdim + n0) * 2 + dd] =
                f2bf((acc[0][mt][reg] + bqv) * (0.125f * L2E));
        }
    // ---- K epilogue: bf16 [b,h,s,d] ----
#pragma unroll
    for (int mt = 0; mt < 4; ++mt)
#pragma unroll
        for (int reg = 0; reg < 4; ++reg) {
            const int srw = s0 + mt * 16 + quad * 4 + reg;
            ko[((size_t)(b * NH + h) * Sdim + srw) * HD + dd] = f2bf(acc[1][mt][reg]);
        }
    // ---- V epilogue: transpose via LDS buf0 (step 31 read buf2: disjoint;
    //      all waves passed iter-31 barrier -> done with buf0 = step 30) ----
    unsigned short* Vl = smem;   // 64*74 shorts = 4736 <= 8192
    {
#pragma unroll
        for (int mt = 0; mt < 4; ++mt) {
            bfx4 p;
#pragma unroll
            for (int reg = 0; reg < 4; ++reg) p[reg] = (short)f2bf(acc[2][mt][reg] + bvv);
            *(bfx4*)(Vl + dd * 74 + mt * 16 + quad * 4) = p;
        }
    }
    __syncthreads();
#pragma unroll
    for (int i = 0; i < 2; ++i) {
        const int t   = tid + 256 * i;
        const int d2  = t >> 3;
        const int off = (t & 7) * 8;
        *(short8*)(vo + ((size_t)(b * NH + h) * HD + d2) * Sdim + s0 + off) =
            *(const short8*)(Vl + d2 * 74 + off);
    }
}

// ---------------------------------------------------------------------------
// Kernel 2: flash attention on 32x32x16 MFMA — EXACT R14 (proven 68-71 us,
// VGPR=64 occupancy cliff edge). Control this round.
// ---------------------------------------------------------------------------
__global__ __launch_bounds__(256) void attn_kernel(
    const unsigned short* __restrict__ kw,
    const unsigned short* __restrict__ vw,
    const float* __restrict__ mb,          // prescaled mask: m*log2e - 12*log2e
    float* __restrict__ out)
{
    __shared__ __align__(16) unsigned short smem[16384];   // 32768 B
    unsigned short* KtA = smem;            // 2 x 4096 shorts (64 keys x 64 d, swizzled)
    unsigned short* VtA = smem + 8192;     // 2 x 4096 shorts (64 d x 64 keys, swizzled)

    const int tid  = threadIdx.x;
    const int wave = tid >> 6;
    const int wq   = wave >> 1;            // q-half 0/1
    const int wk   = wave & 1;             // key-half 0/1
    const int lane = tid & 63;
    const int l5   = lane >> 5;            // lane-half
    const int q31  = lane & 31;            // this lane's q column (C layout)
    const int m7l  = lane & 7;

    const int flat = blockIdx.x;
    const int bh   = flat & 31;
    const int b    = bh >> 4;
    const int h    = bh & 15;
    const int q0   = (flat >> 5) * 64;

    const unsigned short* K  = kw + (size_t)bh * Sdim * HD;   // [key][d]
    const unsigned short* Vg = vw + (size_t)bh * HD * Sdim;   // [d][key]
    const float* mg = mb + (size_t)b * Sdim;

    // ---- Q fragments (B-operand, 32x32x16): lane holds col q31, k = i*16+l5*8 ----
    short8 qf[4];
    {
        const unsigned short* qsrc = (const unsigned short*)out;
        const size_t qbase =
            ((size_t)(b * Sdim + q0 + wq * 32 + q31) * Hdim + h * HD) * 2;
#pragma unroll
        for (int i = 0; i < 4; ++i)
            qf[i] = *(const short8*)(qsrc + qbase + i * 16 + l5 * 8);
    }

    // ---- DMA lane mapping: lane covers row rk, global chunk XOR-swizzled ----
    const int rk = wave * 16 + (lane >> 3);
    const int sw = ((lane & 7) ^ (rk & 7)) * 8;
    const unsigned short* kgp = K  + (size_t)rk * HD   + sw;
    const unsigned short* vgp = Vg + (size_t)rk * Sdim + sw;

    // stage tile 0 -> buffer 0
    {
        unsigned short* Kb = KtA + wave * 1024;
        unsigned short* Vb = VtA + wave * 1024;
        async16(kgp,            Kb);
        async16(kgp + 8 * HD,   Kb + 512);
        async16(vgp,            Vb);
        async16(vgp + 8 * Sdim, Vb + 512);
        kgp += (size_t)64 * HD;
        vgp += 64;
    }

    // tile-invariant LDS read offsets (shorts); row&7 == lane&7 for both
    int kOff[4], vOff[4];
#pragma unroll
    for (int i = 0; i < 4; ++i)
        kOff[i] = (wk * 32 + q31) * 64 + (((2 * i + l5) ^ m7l) * 8);
#pragma unroll
    for (int dblk = 0; dblk < 2; ++dblk)
#pragma unroll
        for (int kc = 0; kc < 2; ++kc)
            vOff[dblk * 2 + kc] =
                (dblk * 32 + q31) * 64 + (((wk * 4 + 2 * kc + l5) ^ m7l) * 8);

    const float* mgp = mg + wk * 32 + l5 * 4;

    float ls[4] = {0.f, 0.f, 0.f, 0.f};   // 4 independent lsum chains
    f32x16 oT[2];                          // O^T per 32-d block; col=q31
#pragma unroll
    for (int dblk = 0; dblk < 2; ++dblk)
#pragma unroll
        for (int r = 0; r < 16; ++r) oT[dblk][r] = 0.f;

    f32x16 z16;                            // loop-invariant zero accumulator
#pragma unroll
    for (int r = 0; r < 16; ++r) z16[r] = 0.f;

    for (int it = 0; it < 32; ++it) {
        __syncthreads();                   // vmcnt drain + barrier: tile ready
        const int kt = it * 64;
        const unsigned short* Kb = KtA + (it & 1) * 4096;
        const unsigned short* Vb = VtA + (it & 1) * 4096;

        if (it < 31) {                     // DMA next tile into other buffer
            unsigned short* Kn = KtA + ((it & 1) ^ 1) * 4096 + wave * 1024;
            unsigned short* Vn = VtA + ((it & 1) ^ 1) * 4096 + wave * 1024;
            async16(kgp,            Kn);
            async16(kgp + 8 * HD,   Kn + 512);
            async16(vgp,            Vn);
            async16(vgp + 8 * Sdim, Vn + 512);
            kgp += (size_t)64 * HD;
            vgp += 64;
        }

        // ---- S^T = K·Q^T: 4 chained 32x32x16 over d; first uses z16 as C ----
        f32x16 st;
        {
            const short8 ka0 = *(const short8*)(Kb + kOff[0]);
            st = __builtin_amdgcn_mfma_f32_32x32x16_bf16(ka0, qf[0], z16, 0, 0, 0);
        }
#pragma unroll
        for (int i = 1; i < 4; ++i) {
            const short8 ka = *(const short8*)(Kb + kOff[i]);
            st = __builtin_amdgcn_mfma_f32_32x32x16_bf16(ka, qf[i], st, 0, 0, 0);
        }

        // ---- raw v_exp_f32 + in-reg bf16 pack; st reg r -> key (r&3)+8*(r>>2)+4*l5
        unsigned int w[8];
#pragma unroll
        for (int j = 0; j < 4; ++j) {
            const floatx4 mv = *(const floatx4*)(mgp + kt + j * 8);
            float e[4];
#pragma unroll
            for (int r = 0; r < 4; ++r)
                e[r] = exp2_raw(st[j * 4 + r] + mv[r]);
            ls[j] += (e[0] + e[1]) + (e[2] + e[3]);
            w[2 * j]     = cvtpk(e[0], e[1]);
            w[2 * j + 1] = cvtpk(e[2], e[3]);
        }

        // ---- cross-half exchange: 4 x v_permlane32_swap ----
        asm("v_permlane32_swap_b32 %0, %1" : "+v"(w[0]), "+v"(w[2]));
        asm("v_permlane32_swap_b32 %0, %1" : "+v"(w[1]), "+v"(w[3]));
        asm("v_permlane32_swap_b32 %0, %1" : "+v"(w[4]), "+v"(w[6]));
        asm("v_permlane32_swap_b32 %0, %1" : "+v"(w[5]), "+v"(w[7]));
        union { unsigned int u[4]; short8 s; } pb0, pb1;
#pragma unroll
        for (int r = 0; r < 4; ++r) { pb0.u[r] = w[r]; pb1.u[r] = w[4 + r]; }

        // ---- O^T += V^T·P^T: 2 d-blocks x 2 key-chunks (keys wk*32+kc*16+..) ----
#pragma unroll
        for (int dblk = 0; dblk < 2; ++dblk) {
            const short8 va0 = *(const short8*)(Vb + vOff[dblk * 2 + 0]);
            oT[dblk] = __builtin_amdgcn_mfma_f32_32x32x16_bf16(va0, pb0.s, oT[dblk], 0, 0, 0);
            const short8 va1 = *(const short8*)(Vb + vOff[dblk * 2 + 1]);
            oT[dblk] = __builtin_amdgcn_mfma_f32_32x32x16_bf16(va1, pb1.s, oT[dblk], 0, 0, 0);
        }
    }

    // ---- combine chains + lane halves: full 32-key sum for this key-half ----
    float lsum = (ls[0] + ls[1]) + (ls[2] + ls[3]);
    lsum += __shfl_xor(lsum, 32);

    __syncthreads();                       // all waves done with K/V buffers

    // ---- cross-wave (key-half) reduction via LDS, then write out ----
    float* Ored = (float*)smem;            // [64 q][68 d] fp32 (17408 B)
    float* Lred = Ored + 64 * 68;          // [64]
    const int qrow = wq * 32 + q31;
    if (wk == 0) {
#pragma unroll
        for (int dblk = 0; dblk < 2; ++dblk)
#pragma unroll
            for (int j = 0; j < 4; ++j) {
                floatx4 v;
#pragma unroll
                for (int r = 0; r < 4; ++r) v[r] = oT[dblk][j * 4 + r];
                *(floatx4*)(Ored + (size_t)qrow * 68 + dblk * 32 + j * 8 + l5 * 4) = v;
            }
        if (lane < 32) Lred[qrow] = lsum;
    }
    __syncthreads();
    if (wk == 1) {
        const float linv = 1.0f / (lsum + Lred[qrow]);
#pragma unroll
        for (int dblk = 0; dblk < 2; ++dblk)
#pragma unroll
            for (int j = 0; j < 4; ++j) {
                const floatx4 o =
                    *(const floatx4*)(Ored + (size_t)qrow * 68 + dblk * 32 + j * 8 + l5 * 4);
                floatx4 r;
#pragma unroll
                for (int t = 0; t < 4; ++t)
                    r[t] = (o[t] + oT[dblk][j * 4 + t]) * linv;
                *(floatx4*)(out + (size_t)(b * Sdim + q0 + qrow) * Hdim
                            + h * HD + dblk * 32 + j * 8 + l5 * 4) = r;
            }
    }
}

extern "C" void kernel_launch(void* const* d_in, const int* in_sizes, int n_in,
                              void* d_out, int out_size, void* d_ws, size_t ws_size,
                              hipStream_t stream) {
    const float* X    = (const float*)d_in[0];
    const float* mask = (const float*)d_in[1];
    const float* Wq   = (const float*)d_in[2];
    const float* bq   = (const float*)d_in[3];
    const float* Wk   = (const float*)d_in[4];
    const float* Wv   = (const float*)d_in[5];
    const float* bv   = (const float*)d_in[6];
    float* out = (float*)d_out;

    // workspace (30.02 MiB): k 8 + v^T 8 + X_bf16 8 + W_bf16 6 + mask2 16KB
    unsigned short* kws = (unsigned short*)d_ws;
    unsigned short* vws = kws + (size_t)4096 * 1024;
    unsigned short* xb  = vws + (size_t)4096 * 1024;
    unsigned short* wb  = xb  + (size_t)2 * Sdim * Hdim;
    float*          mb  = (float*)(wb + (size_t)3 * Hdim * Hdim);

    cast_kernel<<<dim3(2048), 256, 0, stream>>>(X, Wq, Wk, Wv, mask, xb, wb, mb);
    qkv_proj_kernel<<<dim3(16, 64), 256, 0, stream>>>(
        wb, bq, bv, xb, (unsigned short*)d_out, kws, vws);
    attn_kernel<<<dim3(1024), 256, 0, stream>>>(
        kws, vws, mb, out);
}

// Round 18
// 173.514 us; speedup vs baseline: 1.1487x; 1.0680x over previous
//
#include <hip/hip_runtime.h>
#include <hip/hip_bf16.h>

typedef __attribute__((ext_vector_type(4))) short bfx4;
typedef __attribute__((ext_vector_type(8))) short short8;
typedef __attribute__((ext_vector_type(4))) float floatx4;
typedef __attribute__((ext_vector_type(16))) float f32x16;
typedef __attribute__((ext_vector_type(4))) unsigned int uintx4;

constexpr int Sdim = 2048;
constexpr int Hdim = 1024;
constexpr int NH   = 16;
constexpr int HD   = 64;

constexpr float L2E    = 1.4426950408889634f;   // log2(e)
constexpr float SHIFT2 = 17.312340490667562f;   // 12 * log2(e)

// fp32 -> bf16 round-half-up (1 add + shift)
__device__ __forceinline__ unsigned short f2bf(float f) {
    return (unsigned short)((__builtin_bit_cast(unsigned int, f) + 0x8000u) >> 16);
}

// 8 fp32 -> 8 bf16, round-half-up, packed with v_perm_b32
__device__ __forceinline__ short8 cvt8(const float* __restrict__ p) {
    uintx4 a = *(const uintx4*)p;
    uintx4 b = *(const uintx4*)(p + 4);
#pragma unroll
    for (int i = 0; i < 4; ++i) { a[i] += 0x8000u; b[i] += 0x8000u; }
    union { unsigned int u[4]; short8 s; } r;
    r.u[0] = __builtin_amdgcn_perm(a[1], a[0], 0x07060302u);
    r.u[1] = __builtin_amdgcn_perm(a[3], a[2], 0x07060302u);
    r.u[2] = __builtin_amdgcn_perm(b[1], b[0], 0x07060302u);
    r.u[3] = __builtin_amdgcn_perm(b[3], b[2], 0x07060302u);
    return r.s;
}

// async global->LDS, 16 B per lane; LDS dest = uniform base + lane*16
__device__ __forceinline__ void async16(const unsigned short* g, unsigned short* l) {
    __builtin_amdgcn_global_load_lds(
        (const __attribute__((address_space(1))) unsigned int*)g,
        (__attribute__((address_space(3))) unsigned int*)l,
        16, 0, 0);
}

// pack 2 f32 -> 2 bf16 (RNE) in one instruction
__device__ __forceinline__ unsigned int cvtpk(float lo, float hi) {
    unsigned int r;
    asm("v_cvt_pk_bf16_f32 %0, %1, %2" : "=v"(r) : "v"(lo), "v"(hi));
    return r;
}

// bare v_exp_f32: D = 2^S0
__device__ __forceinline__ float exp2_raw(float x) {
    float r;
    asm("v_exp_f32 %0, %1" : "=v"(r) : "v"(x));
    return r;
}

// ---------------------------------------------------------------------------
// Kernel 0: cast X, Wq, Wk, Wv to bf16; prescale mask to m*log2e - 12*log2e.
// (UNCHANGED — control.)
// ---------------------------------------------------------------------------
__global__ __launch_bounds__(256) void cast_kernel(
    const float* __restrict__ X,
    const float* __restrict__ Wq,
    const float* __restrict__ Wk,
    const float* __restrict__ Wv,
    const float* __restrict__ mask,
    unsigned short* __restrict__ xb,
    unsigned short* __restrict__ wb,
    float* __restrict__ mb)
{
    constexpr int XC = (2 * Sdim * Hdim) / 8;   // 524288 8-elem chunks
    constexpr int WC = (Hdim * Hdim) / 8;       // 131072 chunks per W
    constexpr int MC = (2 * Sdim) / 8;          // 512 mask chunks
    const int stride = gridDim.x * blockDim.x;
    for (int c = blockIdx.x * blockDim.x + threadIdx.x; c < XC + 3 * WC + MC; c += stride) {
        if (c < XC + 3 * WC) {
            const float* src;
            unsigned short* dst;
            if (c < XC) {
                src = X + (size_t)c * 8;
                dst = xb + (size_t)c * 8;
            } else {
                const int wc = c - XC;
                const int w  = wc / WC;
                const int o  = wc - w * WC;
                src = (w == 0 ? Wq : (w == 1 ? Wk : Wv)) + (size_t)o * 8;
                dst = wb + (size_t)w * (Hdim * Hdim) + (size_t)o * 8;
            }
            *(short8*)dst = cvt8(src);
        } else {
            const int o = c - XC - 3 * WC;
            floatx4 a = *(const floatx4*)(mask + (size_t)o * 8);
            floatx4 b = *(const floatx4*)(mask + (size_t)o * 8 + 4);
#pragma unroll
            for (int r = 0; r < 4; ++r) {
                a[r] = a[r] * L2E - SHIFT2;
                b[r] = b[r] * L2E - SHIFT2;
            }
            *(floatx4*)(mb + (size_t)o * 8)     = a;
            *(floatx4*)(mb + (size_t)o * 8 + 4) = b;
        }
    }
}

// ---------------------------------------------------------------------------
// Kernel 1: merged Q/K/V projection. R18: BK=64 — 16 steps / 16 barriers
// (half of R14), 24 MFMA per wave per barrier (double). R16 established
// barrier-event count as the operative proj variable (+32K events = +16us);
// this moves it the other way. LDS 2 x 32 KiB = 64 KiB -> 2 blocks/CU
// (8 waves) — acceptable because proj is NOT latency-bound (R17 ring-3
// neutral). Staging: wave stages its own 64x64 tile = 8 async16/step;
// 8-chunk swizzle: src chunk = (lane&7)^(lane>>3), read chunk =
// (kk*4+quad)^(l16&7) -> 8 distinct 16B slots, 2 lanes/bank (free).
// Accumulation order bit-identical to R14.
// grid = (16 heads, 64 m-tiles); block = 256.
// ---------------------------------------------------------------------------
__global__ __launch_bounds__(256, 2) void qkv_proj_kernel(
    const unsigned short* __restrict__ wbf,   // [3][1024][1024] bf16
    const float* __restrict__ bq,
    const float* __restrict__ bv,
    const unsigned short* __restrict__ xbf,   // [4096][1024] bf16
    unsigned short* __restrict__ qo,          // = d_out viewed as ushort
    unsigned short* __restrict__ ko,
    unsigned short* __restrict__ vo)
{
    __shared__ __align__(16) unsigned short smem[2 * 16384];  // 65536 B
    // buffer p: +p*16384 shorts; tiles (64 rows x 64 shorts):
    //   X +0, W0 +4096, W1 +8192, W2 +12288  (= wave*4096)

    const int tid  = threadIdx.x;
    const int wave = tid >> 6;
    const int lane = tid & 63;
    const int quad = lane >> 4;
    const int l16  = lane & 15;

    const int h  = blockIdx.x;
    const int n0 = h * 64;
    const int m0 = blockIdx.y * 64;

    floatx4 acc[3][4];                   // [matrix][m-tile]
#pragma unroll
    for (int g = 0; g < 3; ++g)
#pragma unroll
        for (int mt = 0; mt < 4; ++mt) acc[g][mt] = (floatx4){0.f, 0.f, 0.f, 0.f};

    // ---- DMA source mapping: 8 lanes/row; lane -> row j*8 + (lane>>3),
    //      src 16B chunk = (lane&7) ^ (lane>>3)  (j*8 drops out of row&7)
    const int drow8 = lane >> 3;             // 0..7
    const unsigned short* gbase = (wave == 0)
        ? xbf + (size_t)m0 * Hdim
        : wbf + (size_t)(wave - 1) * (Hdim * Hdim) + (size_t)n0 * Hdim;
    const unsigned short* gp =
        gbase + (size_t)drow8 * Hdim + (((lane & 7) ^ drow8) * 8);

    // stage step 0 -> buffer 0 (wave stages its own 8 KiB tile)
    {
        unsigned short* db = smem + wave * 4096;
#pragma unroll
        for (int j = 0; j < 8; ++j)
            async16(gp + (size_t)(j * 8) * Hdim, db + j * 512);
    }

    // fragment read offsets (shorts): row = {mt|wave}*16 + l16 (stride 64),
    // chunk = (kk*4 + quad) ^ (l16&7)
    const int m7  = l16 & 7;
    int csw[2];
#pragma unroll
    for (int kk = 0; kk < 2; ++kk) csw[kk] = ((kk * 4 + quad) ^ m7) * 8;
    const int browoff = (wave * 16 + l16) * 64;

    for (int s = 0; s < 16; ++s) {
        __syncthreads();                              // drain DMA: tile s ready
        const unsigned short* buf = smem + (s & 1) * 16384;

        if (s < 15) {                                 // DMA next step -> other buffer
            unsigned short* nb = smem + ((s & 1) ^ 1) * 16384 + wave * 4096;
            const unsigned short* g = gp + (s + 1) * 64;
#pragma unroll
            for (int j = 0; j < 8; ++j)
                async16(g + (size_t)(j * 8) * Hdim, nb + j * 512);
        }

#pragma unroll
        for (int kk = 0; kk < 2; ++kk) {
            const short8 b0 = *(const short8*)(buf +  4096 + browoff + csw[kk]);
            const short8 b1 = *(const short8*)(buf +  8192 + browoff + csw[kk]);
            const short8 b2 = *(const short8*)(buf + 12288 + browoff + csw[kk]);
#pragma unroll
            for (int mt = 0; mt < 4; ++mt) {
                const short8 af = *(const short8*)(buf + (mt * 16 + l16) * 64 + csw[kk]);
                acc[0][mt] = __builtin_amdgcn_mfma_f32_16x16x32_bf16(af, b0, acc[0][mt], 0, 0, 0);
                acc[1][mt] = __builtin_amdgcn_mfma_f32_16x16x32_bf16(af, b1, acc[1][mt], 0, 0, 0);
                acc[2][mt] = __builtin_amdgcn_mfma_f32_16x16x32_bf16(af, b2, acc[2][mt], 0, 0, 0);
            }
        }
    }

    const int b  = m0 >> 11;
    const int s0 = m0 & 2047;
    const int dd = wave * 16 + l16;

    // ---- Q epilogue: bf16, scale = 0.125*log2e (exp2-ready) ----
    {
        const float bqv = bq[n0 + dd];
#pragma unroll
        for (int mt = 0; mt < 4; ++mt)
#pragma unroll
            for (int reg = 0; reg < 4; ++reg) {
                const int srw = s0 + mt * 16 + quad * 4 + reg;
                qo[((size_t)(b * Sdim + srw) * Hdim + n0) * 2 + dd] =
                    f2bf((acc[0][mt][reg] + bqv) * (0.125f * L2E));
            }
    }
    // ---- K epilogue: bf16 [b,h,s,d] ----
#pragma unroll
    for (int mt = 0; mt < 4; ++mt)
#pragma unroll
        for (int reg = 0; reg < 4; ++reg) {
            const int srw = s0 + mt * 16 + quad * 4 + reg;
            ko[((size_t)(b * NH + h) * Sdim + srw) * HD + dd] = f2bf(acc[1][mt][reg]);
        }
    // ---- V epilogue: transpose via LDS buf0 (step 15 read buf1: disjoint) ----
    unsigned short* Vl = smem;   // 64*74 shorts = 4736 <= 16384
    {
        const float bvv = bv[n0 + dd];
#pragma unroll
        for (int mt = 0; mt < 4; ++mt) {
            bfx4 p;
#pragma unroll
            for (int reg = 0; reg < 4; ++reg) p[reg] = (short)f2bf(acc[2][mt][reg] + bvv);
            *(bfx4*)(Vl + dd * 74 + mt * 16 + quad * 4) = p;
        }
    }
    __syncthreads();
#pragma unroll
    for (int i = 0; i < 2; ++i) {
        const int t   = tid + 256 * i;
        const int d2  = t >> 3;
        const int off = (t & 7) * 8;
        *(short8*)(vo + ((size_t)(b * NH + h) * HD + d2) * Sdim + s0 + off) =
            *(const short8*)(Vl + d2 * 74 + off);
    }
}

// ---------------------------------------------------------------------------
// Kernel 2: flash attention on 32x32x16 MFMA — EXACT R14 (proven 68-71 us).
// Control this round.
// ---------------------------------------------------------------------------
__global__ __launch_bounds__(256) void attn_kernel(
    const unsigned short* __restrict__ kw,
    const unsigned short* __restrict__ vw,
    const float* __restrict__ mb,          // prescaled mask: m*log2e - 12*log2e
    float* __restrict__ out)
{
    __shared__ __align__(16) unsigned short smem[16384];   // 32768 B
    unsigned short* KtA = smem;            // 2 x 4096 shorts (64 keys x 64 d, swizzled)
    unsigned short* VtA = smem + 8192;     // 2 x 4096 shorts (64 d x 64 keys, swizzled)

    const int tid  = threadIdx.x;
    const int wave = tid >> 6;
    const int wq   = wave >> 1;            // q-half 0/1
    const int wk   = wave & 1;             // key-half 0/1
    const int lane = tid & 63;
    const int l5   = lane >> 5;            // lane-half
    const int q31  = lane & 31;            // this lane's q column (C layout)
    const int m7l  = lane & 7;

    const int flat = blockIdx.x;
    const int bh   = flat & 31;
    const int b    = bh >> 4;
    const int h    = bh & 15;
    const int q0   = (flat >> 5) * 64;

    const unsigned short* K  = kw + (size_t)bh * Sdim * HD;   // [key][d]
    const unsigned short* Vg = vw + (size_t)bh * HD * Sdim;   // [d][key]
    const float* mg = mb + (size_t)b * Sdim;

    // ---- Q fragments (B-operand, 32x32x16): lane holds col q31, k = i*16+l5*8 ----
    short8 qf[4];
    {
        const unsigned short* qsrc = (const unsigned short*)out;
        const size_t qbase =
            ((size_t)(b * Sdim + q0 + wq * 32 + q31) * Hdim + h * HD) * 2;
#pragma unroll
        for (int i = 0; i < 4; ++i)
            qf[i] = *(const short8*)(qsrc + qbase + i * 16 + l5 * 8);
    }

    // ---- DMA lane mapping: lane covers row rk, global chunk XOR-swizzled ----
    const int rk = wave * 16 + (lane >> 3);
    const int sw = ((lane & 7) ^ (rk & 7)) * 8;
    const unsigned short* kgp = K  + (size_t)rk * HD   + sw;
    const unsigned short* vgp = Vg + (size_t)rk * Sdim + sw;

    // stage tile 0 -> buffer 0
    {
        unsigned short* Kb = KtA + wave * 1024;
        unsigned short* Vb = VtA + wave * 1024;
        async16(kgp,            Kb);
        async16(kgp + 8 * HD,   Kb + 512);
        async16(vgp,            Vb);
        async16(vgp + 8 * Sdim, Vb + 512);
        kgp += (size_t)64 * HD;
        vgp += 64;
    }

    // tile-invariant LDS read offsets (shorts); row&7 == lane&7 for both
    int kOff[4], vOff[4];
#pragma unroll
    for (int i = 0; i < 4; ++i)
        kOff[i] = (wk * 32 + q31) * 64 + (((2 * i + l5) ^ m7l) * 8);
#pragma unroll
    for (int dblk = 0; dblk < 2; ++dblk)
#pragma unroll
        for (int kc = 0; kc < 2; ++kc)
            vOff[dblk * 2 + kc] =
                (dblk * 32 + q31) * 64 + (((wk * 4 + 2 * kc + l5) ^ m7l) * 8);

    const float* mgp = mg + wk * 32 + l5 * 4;

    float ls[4] = {0.f, 0.f, 0.f, 0.f};   // 4 independent lsum chains
    f32x16 oT[2];                          // O^T per 32-d block; col=q31
#pragma unroll
    for (int dblk = 0; dblk < 2; ++dblk)
#pragma unroll
        for (int r = 0; r < 16; ++r) oT[dblk][r] = 0.f;

    f32x16 z16;                            // loop-invariant zero accumulator
#pragma unroll
    for (int r = 0; r < 16; ++r) z16[r] = 0.f;

    for (int it = 0; it < 32; ++it) {
        __syncthreads();                   // vmcnt drain + barrier: tile ready
        const int kt = it * 64;
        const unsigned short* Kb = KtA + (it & 1) * 4096;
        const unsigned short* Vb = VtA + (it & 1) * 4096;

        if (it < 31) {                     // DMA next tile into other buffer
            unsigned short* Kn = KtA + ((it & 1) ^ 1) * 4096 + wave * 1024;
            unsigned short* Vn = VtA + ((it & 1) ^ 1) * 4096 + wave * 1024;
            async16(kgp,            Kn);
            async16(kgp + 8 * HD,   Kn + 512);
            async16(vgp,            Vn);
            async16(vgp + 8 * Sdim, Vn + 512);
            kgp += (size_t)64 * HD;
            vgp += 64;
        }

        // ---- S^T = K·Q^T: 4 chained 32x32x16 over d; first uses z16 as C ----
        f32x16 st;
        {
            const short8 ka0 = *(const short8*)(Kb + kOff[0]);
            st = __builtin_amdgcn_mfma_f32_32x32x16_bf16(ka0, qf[0], z16, 0, 0, 0);
        }
#pragma unroll
        for (int i = 1; i < 4; ++i) {
            const short8 ka = *(const short8*)(Kb + kOff[i]);
            st = __builtin_amdgcn_mfma_f32_32x32x16_bf16(ka, qf[i], st, 0, 0, 0);
        }

        // ---- raw v_exp_f32 + in-reg bf16 pack; st reg r -> key (r&3)+8*(r>>2)+4*l5
        unsigned int w[8];
#pragma unroll
        for (int j = 0; j < 4; ++j) {
            const floatx4 mv = *(const floatx4*)(mgp + kt + j * 8);
            float e[4];
#pragma unroll
            for (int r = 0; r < 4; ++r)
                e[r] = exp2_raw(st[j * 4 + r] + mv[r]);
            ls[j] += (e[0] + e[1]) + (e[2] + e[3]);
            w[2 * j]     = cvtpk(e[0], e[1]);
            w[2 * j + 1] = cvtpk(e[2], e[3]);
        }

        // ---- cross-half exchange: 4 x v_permlane32_swap ----
        asm("v_permlane32_swap_b32 %0, %1" : "+v"(w[0]), "+v"(w[2]));
        asm("v_permlane32_swap_b32 %0, %1" : "+v"(w[1]), "+v"(w[3]));
        asm("v_permlane32_swap_b32 %0, %1" : "+v"(w[4]), "+v"(w[6]));
        asm("v_permlane32_swap_b32 %0, %1" : "+v"(w[5]), "+v"(w[7]));
        union { unsigned int u[4]; short8 s; } pb0, pb1;
#pragma unroll
        for (int r = 0; r < 4; ++r) { pb0.u[r] = w[r]; pb1.u[r] = w[4 + r]; }

        // ---- O^T += V^T·P^T: 2 d-blocks x 2 key-chunks (keys wk*32+kc*16+..) ----
#pragma unroll
        for (int dblk = 0; dblk < 2; ++dblk) {
            const short8 va0 = *(const short8*)(Vb + vOff[dblk * 2 + 0]);
            oT[dblk] = __builtin_amdgcn_mfma_f32_32x32x16_bf16(va0, pb0.s, oT[dblk], 0, 0, 0);
            const short8 va1 = *(const short8*)(Vb + vOff[dblk * 2 + 1]);
            oT[dblk] = __builtin_amdgcn_mfma_f32_32x32x16_bf16(va1, pb1.s, oT[dblk], 0, 0, 0);
        }
    }

    // ---- combine chains + lane halves: full 32-key sum for this key-half ----
    float lsum = (ls[0] + ls[1]) + (ls[2] + ls[3]);
    lsum += __shfl_xor(lsum, 32);

    __syncthreads();                       // all waves done with K/V buffers

    // ---- cross-wave (key-half) reduction via LDS, then write out ----
    float* Ored = (float*)smem;            // [64 q][68 d] fp32 (17408 B)
    float* Lred = Ored + 64 * 68;          // [64]
    const int qrow = wq * 32 + q31;
    if (wk == 0) {
#pragma unroll
        for (int dblk = 0; dblk < 2; ++dblk)
#pragma unroll
            for (int j = 0; j < 4; ++j) {
                floatx4 v;
#pragma unroll
                for (int r = 0; r < 4; ++r) v[r] = oT[dblk][j * 4 + r];
                *(floatx4*)(Ored + (size_t)qrow * 68 + dblk * 32 + j * 8 + l5 * 4) = v;
            }
        if (lane < 32) Lred[qrow] = lsum;
    }
    __syncthreads();
    if (wk == 1) {
        const float linv = 1.0f / (lsum + Lred[qrow]);
#pragma unroll
        for (int dblk = 0; dblk < 2; ++dblk)
#pragma unroll
            for (int j = 0; j < 4; ++j) {
                const floatx4 o =
                    *(const floatx4*)(Ored + (size_t)qrow * 68 + dblk * 32 + j * 8 + l5 * 4);
                floatx4 r;
#pragma unroll
                for (int t = 0; t < 4; ++t)
                    r[t] = (o[t] + oT[dblk][j * 4 + t]) * linv;
                *(floatx4*)(out + (size_t)(b * Sdim + q0 + qrow) * Hdim
                            + h * HD + dblk * 32 + j * 8 + l5 * 4) = r;
            }
    }
}

extern "C" void kernel_launch(void* const* d_in, const int* in_sizes, int n_in,
                              void* d_out, int out_size, void* d_ws, size_t ws_size,
                              hipStream_t stream) {
    const float* X    = (const float*)d_in[0];
    const float* mask = (const float*)d_in[1];
    const float* Wq   = (const float*)d_in[2];
    const float* bq   = (const float*)d_in[3];
    const float* Wk   = (const float*)d_in[4];
    const float* Wv   = (const float*)d_in[5];
    const float* bv   = (const float*)d_in[6];
    float* out = (float*)d_out;

    // workspace (30.02 MiB): k 8 + v^T 8 + X_bf16 8 + W_bf16 6 + mask2 16KB
    unsigned short* kws = (unsigned short*)d_ws;
    unsigned short* vws = kws + (size_t)4096 * 1024;
    unsigned short* xb  = vws + (size_t)4096 * 1024;
    unsigned short* wb  = xb  + (size_t)2 * Sdim * Hdim;
    float*          mb  = (float*)(wb + (size_t)3 * Hdim * Hdim);

    cast_kernel<<<dim3(2048), 256, 0, stream>>>(X, Wq, Wk, Wv, mask, xb, wb, mb);
    qkv_proj_kernel<<<dim3(16, 64), 256, 0, stream>>>(
        wb, bq, bv, xb, (unsigned short*)d_out, kws, vws);
    attn_kernel<<<dim3(1024), 256, 0, stream>>>(
        kws, vws, mb, out);
}